// Round 1
// baseline (1151.891 us; speedup 1.0000x reference)
//
#include <hip/hip_runtime.h>
#include <hip/hip_bf16.h>

typedef unsigned short u16;
typedef unsigned int u32;

#define NB 16
#define CCH 256
#define NHEADS 8
#define DD 64
#define NPOS 4096
#define QKV_OUT 512
#define QK_SCALE 0.35355339059327373f

// ---------- bf16 helpers (bit-exact conversions, RNE pack) ----------
__device__ __forceinline__ float bf2f(u32 u) {
  union { u32 i; float f; } x; x.i = u << 16; return x.f;
}
__device__ __forceinline__ u16 f2bf(float f) {
  union { float f; u32 i; } x; x.f = f;
  u32 r = x.i + 0x7fffu + ((x.i >> 16) & 1u);
  return (u16)(r >> 16);
}
__device__ __forceinline__ void unpack8(uint4 r, float* v) {
  v[0] = bf2f(r.x & 0xffffu); v[1] = bf2f(r.x >> 16);
  v[2] = bf2f(r.y & 0xffffu); v[3] = bf2f(r.y >> 16);
  v[4] = bf2f(r.z & 0xffffu); v[5] = bf2f(r.z >> 16);
  v[6] = bf2f(r.w & 0xffffu); v[7] = bf2f(r.w >> 16);
}

template<typename BT> __device__ __forceinline__ float4 loadB4(const BT* p);
template<> __device__ __forceinline__ float4 loadB4<float>(const float* p) {
  return *(const float4*)p;
}
template<> __device__ __forceinline__ float4 loadB4<u16>(const u16* p) {
  ushort4 u = *(const ushort4*)p;
  return make_float4(bf2f(u.x), bf2f(u.y), bf2f(u.z), bf2f(u.w));
}

template<typename CT> __device__ __forceinline__ void storeC4(CT* p, float a, float b, float c, float d);
template<> __device__ __forceinline__ void storeC4<float>(float* p, float a, float b, float c, float d) {
  *(float4*)p = make_float4(a, b, c, d);
}
template<> __device__ __forceinline__ void storeC4<u16>(u16* p, float a, float b, float c, float d) {
  ushort4 o; o.x = f2bf(a); o.y = f2bf(b); o.z = f2bf(c); o.w = f2bf(d);
  *(ushort4*)p = o;
}

// ---------- K1/K6: C[m,n] = (sum_k A[m,k]*B[k,n] + bias[m]) * scale ----------
// A fp32 row-major [M,K] (k contig), B [K, 4096] (n contig), 64x64 tile, BK=32.
template<typename BT, typename CT>
__global__ __launch_bounds__(256) void gemm_an(
    const float* __restrict__ A, long aBatch,
    const BT* __restrict__ Bm, long bBatch,
    const float* __restrict__ bias,
    CT* __restrict__ Cm, long cBatch,
    int K, float scale)
{
  const int NN = NPOS;
  int b = blockIdx.z;
  A  += (long)b * aBatch;
  Bm += (long)b * bBatch;
  Cm += (long)b * cBatch;
  int m0 = blockIdx.y * 64, n0 = blockIdx.x * 64;

  __shared__ float As[32][68];  // [kk][m], transposed store
  __shared__ float Bs[32][68];  // [kk][n]
  int tid = threadIdx.x;
  int tx = tid & 15, ty = tid >> 4;
  float acc[4][4] = {};

  for (int k0 = 0; k0 < K; k0 += 32) {
    // stage A tile 64x32 (2 float4/thread), transpose into As[kk][m]
    #pragma unroll
    for (int u = 0; u < 2; ++u) {
      int idx = u * 256 + tid;
      int row = idx >> 3;
      int cc  = (idx & 7) << 2;
      float4 av = *(const float4*)&A[(long)(m0 + row) * K + k0 + cc];
      As[cc + 0][row] = av.x; As[cc + 1][row] = av.y;
      As[cc + 2][row] = av.z; As[cc + 3][row] = av.w;
    }
    // stage B tile 32x64 (2 float4/thread equivalents)
    #pragma unroll
    for (int u = 0; u < 2; ++u) {
      int idx = u * 256 + tid;
      int kk = idx >> 4;
      int nc = (idx & 15) << 2;
      float4 bv = loadB4(Bm + (long)(k0 + kk) * NN + n0 + nc);
      *(float4*)&Bs[kk][nc] = bv;
    }
    __syncthreads();
    #pragma unroll
    for (int kk = 0; kk < 32; ++kk) {
      float4 a4 = *(const float4*)&As[kk][ty << 2];
      float4 b4 = *(const float4*)&Bs[kk][tx << 2];
      float av[4] = {a4.x, a4.y, a4.z, a4.w};
      float bv[4] = {b4.x, b4.y, b4.z, b4.w};
      #pragma unroll
      for (int i = 0; i < 4; ++i)
        #pragma unroll
        for (int j = 0; j < 4; ++j)
          acc[i][j] += av[i] * bv[j];
    }
    __syncthreads();
  }
  #pragma unroll
  for (int i = 0; i < 4; ++i) {
    int m = m0 + (ty << 2) + i;
    float bi = bias[m];
    storeC4(&Cm[(long)m * NN + n0 + (tx << 2)],
            (acc[i][0] + bi) * scale, (acc[i][1] + bi) * scale,
            (acc[i][2] + bi) * scale, (acc[i][3] + bi) * scale);
  }
}

// ---------- K2: softmax over n (4096) per row, in-place on bf16 ----------
__global__ __launch_bounds__(256) void softmax_n(u16* __restrict__ kd) {
  long row = blockIdx.x;            // 16*8*64 = 8192 rows
  u16* p = kd + row * NPOS;
  int tid = threadIdx.x;
  int lane = tid & 63, wid = tid >> 6;

  float v[16];
  uint4 r0 = *(const uint4*)(p + tid * 16);
  uint4 r1 = *(const uint4*)(p + tid * 16 + 8);
  unpack8(r0, v); unpack8(r1, v + 8);

  float mx = -1e30f;
  #pragma unroll
  for (int u = 0; u < 16; ++u) mx = fmaxf(mx, v[u]);
  #pragma unroll
  for (int off = 32; off > 0; off >>= 1) mx = fmaxf(mx, __shfl_xor(mx, off));
  __shared__ float smx[4], ssum[4];
  if (lane == 0) smx[wid] = mx;
  __syncthreads();
  mx = fmaxf(fmaxf(smx[0], smx[1]), fmaxf(smx[2], smx[3]));

  float s = 0.f;
  #pragma unroll
  for (int u = 0; u < 16; ++u) { v[u] = __expf(v[u] - mx); s += v[u]; }
  #pragma unroll
  for (int off = 32; off > 0; off >>= 1) s += __shfl_xor(s, off);
  if (lane == 0) ssum[wid] = s;
  __syncthreads();
  s = ssum[0] + ssum[1] + ssum[2] + ssum[3];
  float inv = 1.f / s;

  uint4 o0, o1;
  o0.x = (u32)f2bf(v[0]*inv)  | ((u32)f2bf(v[1]*inv)  << 16);
  o0.y = (u32)f2bf(v[2]*inv)  | ((u32)f2bf(v[3]*inv)  << 16);
  o0.z = (u32)f2bf(v[4]*inv)  | ((u32)f2bf(v[5]*inv)  << 16);
  o0.w = (u32)f2bf(v[6]*inv)  | ((u32)f2bf(v[7]*inv)  << 16);
  o1.x = (u32)f2bf(v[8]*inv)  | ((u32)f2bf(v[9]*inv)  << 16);
  o1.y = (u32)f2bf(v[10]*inv) | ((u32)f2bf(v[11]*inv) << 16);
  o1.z = (u32)f2bf(v[12]*inv) | ((u32)f2bf(v[13]*inv) << 16);
  o1.w = (u32)f2bf(v[14]*inv) | ((u32)f2bf(v[15]*inv) << 16);
  *(uint4*)(p + tid * 16) = o0;
  *(uint4*)(p + tid * 16 + 8) = o1;
}

// ---------- K3: ctx_partial[ns][bh][d][e] = sum_{n in slice} ksm[d,n]*v[e,n] ----------
__global__ __launch_bounds__(256) void ctx_kernel(
    const u16* __restrict__ ksm, const u16* __restrict__ vv, float* __restrict__ ctxp)
{
  int ns = blockIdx.x;   // 4 n-splits of 1024
  int bh = blockIdx.y;   // 128
  const u16* kp = ksm + (long)bh * DD * NPOS + ns * 1024;
  const u16* vp = vv  + (long)bh * DD * NPOS + ns * 1024;
  __shared__ float Ks[64][65], Vs[64][65];
  int tid = threadIdx.x, tx = tid & 15, ty = tid >> 4;
  float acc[4][4] = {};

  int row = tid >> 2;
  int nc  = (tid & 3) << 4;
  for (int c = 0; c < 16; ++c) {
    int nb = c * 64;
    float t[16];
    uint4 a0 = *(const uint4*)(kp + (long)row * NPOS + nb + nc);
    uint4 a1 = *(const uint4*)(kp + (long)row * NPOS + nb + nc + 8);
    unpack8(a0, t); unpack8(a1, t + 8);
    #pragma unroll
    for (int u = 0; u < 16; ++u) Ks[row][nc + u] = t[u];
    uint4 b0 = *(const uint4*)(vp + (long)row * NPOS + nb + nc);
    uint4 b1 = *(const uint4*)(vp + (long)row * NPOS + nb + nc + 8);
    unpack8(b0, t); unpack8(b1, t + 8);
    #pragma unroll
    for (int u = 0; u < 16; ++u) Vs[row][nc + u] = t[u];
    __syncthreads();
    #pragma unroll 8
    for (int nn = 0; nn < 64; ++nn) {
      float a[4], b[4];
      #pragma unroll
      for (int i = 0; i < 4; ++i) a[i] = Ks[(ty << 2) + i][nn];
      #pragma unroll
      for (int j = 0; j < 4; ++j) b[j] = Vs[(tx << 2) + j][nn];
      #pragma unroll
      for (int i = 0; i < 4; ++i)
        #pragma unroll
        for (int j = 0; j < 4; ++j)
          acc[i][j] += a[i] * b[j];
    }
    __syncthreads();
  }
  float* cp = ctxp + ((long)ns * 128 + bh) * 64 * 64;
  #pragma unroll
  for (int i = 0; i < 4; ++i) {
    int d = (ty << 2) + i;
    *(float4*)&cp[d * 64 + (tx << 2)] =
        make_float4(acc[i][0], acc[i][1], acc[i][2], acc[i][3]);
  }
}

// ---------- K4: Wc[b,co,h*64+d] = sum_e Wo[co,h*64+e] * ctx[b,h,d,e] ----------
__global__ __launch_bounds__(256) void wc_kernel(
    const float* __restrict__ ctxp, const float* __restrict__ Wo, float* __restrict__ Wc)
{
  int bh = blockIdx.x;            // 128
  int bb = bh >> 3, h = bh & 7;
  __shared__ float Cs[64][65];    // [d][e] summed ctx
  __shared__ float Ws[64][65];    // [co(64-chunk)][e]
  int tid = threadIdx.x, tx = tid & 15, ty = tid >> 4;

  {
    int row = tid >> 2;
    int ec  = (tid & 3) << 4;
    #pragma unroll
    for (int u = 0; u < 4; ++u) {
      float4 s = make_float4(0, 0, 0, 0);
      #pragma unroll
      for (int si = 0; si < 4; ++si) {
        float4 t = *(const float4*)&ctxp[(((long)si * 128 + bh) * 64 + row) * 64 + ec + u * 4];
        s.x += t.x; s.y += t.y; s.z += t.z; s.w += t.w;
      }
      Cs[row][ec + u*4 + 0] = s.x; Cs[row][ec + u*4 + 1] = s.y;
      Cs[row][ec + u*4 + 2] = s.z; Cs[row][ec + u*4 + 3] = s.w;
    }
  }
  for (int cc = 0; cc < 4; ++cc) {
    __syncthreads();
    {
      int row = tid >> 2;
      int ec  = (tid & 3) << 4;
      #pragma unroll
      for (int u = 0; u < 4; ++u) {
        float4 w = *(const float4*)&Wo[(long)(cc * 64 + row) * 512 + h * 64 + ec + u * 4];
        Ws[row][ec + u*4 + 0] = w.x; Ws[row][ec + u*4 + 1] = w.y;
        Ws[row][ec + u*4 + 2] = w.z; Ws[row][ec + u*4 + 3] = w.w;
      }
    }
    __syncthreads();
    float acc[4][4] = {};
    #pragma unroll 8
    for (int e = 0; e < 64; ++e) {
      float a[4], b[4];
      #pragma unroll
      for (int i = 0; i < 4; ++i) a[i] = Ws[(ty << 2) + i][e];
      #pragma unroll
      for (int j = 0; j < 4; ++j) b[j] = Cs[(tx << 2) + j][e];
      #pragma unroll
      for (int i = 0; i < 4; ++i)
        #pragma unroll
        for (int j = 0; j < 4; ++j)
          acc[i][j] += a[i] * b[j];
    }
    #pragma unroll
    for (int i = 0; i < 4; ++i) {
      int co = cc * 64 + (ty << 2) + i;
      *(float4*)&Wc[((long)bb * 256 + co) * 512 + h * 64 + (tx << 2)] =
          make_float4(acc[i][0], acc[i][1], acc[i][2], acc[i][3]);
    }
  }
}

// ---------- K5: softmax over d (64, stride 4096) per (b,h,n), in-place bf16 ----------
__global__ __launch_bounds__(256) void softmax_d(u16* __restrict__ q) {
  long gid = (long)blockIdx.x * 256 + threadIdx.x;   // 16*8*4096 threads
  int n = (int)(gid & (NPOS - 1));
  long bh = gid >> 12;
  u16* p = q + bh * DD * NPOS + n;
  float v[64];
  float mx = -1e30f;
  #pragma unroll
  for (int d = 0; d < 64; ++d) { v[d] = bf2f(p[(long)d * NPOS]); mx = fmaxf(mx, v[d]); }
  float s = 0.f;
  #pragma unroll
  for (int d = 0; d < 64; ++d) { v[d] = __expf(v[d] - mx); s += v[d]; }
  float inv = 1.f / s;
  #pragma unroll
  for (int d = 0; d < 64; ++d) p[(long)d * NPOS] = f2bf(v[d] * inv);
}

// ---------- launch ----------
extern "C" void kernel_launch(void* const* d_in, const int* in_sizes, int n_in,
                              void* d_out, int out_size, void* d_ws, size_t ws_size,
                              hipStream_t stream) {
  (void)in_sizes; (void)n_in; (void)out_size; (void)ws_size;
  const float* x  = (const float*)d_in[0];
  const float* Wq = (const float*)d_in[1];
  const float* bq = (const float*)d_in[2];
  const float* Wk = (const float*)d_in[3];
  const float* bk = (const float*)d_in[4];
  const float* Wv = (const float*)d_in[5];
  const float* bv = (const float*)d_in[6];
  const float* Wo = (const float*)d_in[7];
  const float* bo = (const float*)d_in[8];
  float* out = (float*)d_out;

  char* ws = (char*)d_ws;
  u16*   qb   = (u16*)(ws);                         // 64 MB  bf16 [16][512][4096]
  u16*   kb   = (u16*)(ws + 67108864L);             // 64 MB
  u16*   vb   = (u16*)(ws + 134217728L);            // 64 MB
  float* ctxp = (float*)(ws + 201326592L);          // 8 MB   [4][128][64][64]
  float* Wc   = (float*)(ws + 209715200L);          // 8 MB   [16][256][512]

  dim3 blk(256);
  long bBx = (long)CCH * NPOS;        // x batch stride
  long cBqkv = (long)QKV_OUT * NPOS;  // q/k/v batch stride

  // K1: projections (M=512, K=256)
  hipLaunchKernelGGL(HIP_KERNEL_NAME(gemm_an<float, u16>), dim3(64, 8, NB), blk, 0, stream,
                     Wq, 0L, x, bBx, bq, qb, cBqkv, CCH, QK_SCALE);
  hipLaunchKernelGGL(HIP_KERNEL_NAME(gemm_an<float, u16>), dim3(64, 8, NB), blk, 0, stream,
                     Wk, 0L, x, bBx, bk, kb, cBqkv, CCH, QK_SCALE);
  hipLaunchKernelGGL(HIP_KERNEL_NAME(gemm_an<float, u16>), dim3(64, 8, NB), blk, 0, stream,
                     Wv, 0L, x, bBx, bv, vb, cBqkv, CCH, 1.0f);
  // K2: k softmax over n
  hipLaunchKernelGGL(softmax_n, dim3(NB * NHEADS * DD), blk, 0, stream, kb);
  // K3: ctx partials
  hipLaunchKernelGGL(ctx_kernel, dim3(4, NB * NHEADS), blk, 0, stream, kb, vb, ctxp);
  // K4: fold ctx into Wo -> Wc
  hipLaunchKernelGGL(wc_kernel, dim3(NB * NHEADS), blk, 0, stream, ctxp, Wo, Wc);
  // K5: q softmax over d
  hipLaunchKernelGGL(softmax_d, dim3(NB * NHEADS * NPOS / 256), blk, 0, stream, qb);
  // K6: y = Wc[b] @ q_sm[b] + bo  (M=256, K=512)
  hipLaunchKernelGGL(HIP_KERNEL_NAME(gemm_an<u16, float>), dim3(64, 4, NB), blk, 0, stream,
                     Wc, (long)256 * 512, qb, (long)QKV_OUT * NPOS, bo, out, (long)CCH * NPOS,
                     QKV_OUT, 1.0f);
}

// Round 2
// 359.389 us; speedup vs baseline: 3.2051x; 3.2051x over previous
//
#include <hip/hip_runtime.h>
#include <hip/hip_bf16.h>

typedef unsigned short u16;
typedef unsigned int u32;
typedef __attribute__((ext_vector_type(8))) short bf16x8;
typedef __attribute__((ext_vector_type(4))) float f32x4;

#define NB 16
#define NHEADS 8
#define NPOS 4096
#define QK_SCALE 0.35355339059327373f

// ---------- bf16 helpers ----------
__device__ __forceinline__ float bf2f(u32 u) {
  union { u32 i; float f; } x; x.i = u << 16; return x.f;
}
__device__ __forceinline__ u16 f2bf(float f) {
  union { float f; u32 i; } x; x.f = f;
  u32 r = x.i + 0x7fffu + ((x.i >> 16) & 1u);
  return (u16)(r >> 16);
}
__device__ __forceinline__ void unpack8(uint4 r, float* v) {
  v[0] = bf2f(r.x & 0xffffu); v[1] = bf2f(r.x >> 16);
  v[2] = bf2f(r.y & 0xffffu); v[3] = bf2f(r.y >> 16);
  v[4] = bf2f(r.z & 0xffffu); v[5] = bf2f(r.z >> 16);
  v[6] = bf2f(r.w & 0xffffu); v[7] = bf2f(r.w >> 16);
}

// async global->LDS, 16B per lane; lds dst is wave-uniform base (+lane*16 by HW)
__device__ __forceinline__ void async16(u16* ldst, const u16* gsrc) {
  __builtin_amdgcn_global_load_lds(
      (const __attribute__((address_space(1))) unsigned int*)gsrc,
      (__attribute__((address_space(3))) unsigned int*)ldst, 16, 0, 0);
}

// ---------- x: [16][256][4096] f32  ->  xT: [16][4096][256] bf16 ----------
__global__ __launch_bounds__(256) void transpose_x(const float* __restrict__ x,
                                                   u16* __restrict__ xT) {
  int b = blockIdx.z;
  int c0 = blockIdx.y * 64;
  int n0 = blockIdx.x * 64;
  const float* xp = x + ((long)b * 256 + c0) * 4096 + n0;
  u16* op = xT + ((long)b * 4096 + n0) * 256 + c0;
  __shared__ float T[64][65];
  int t = threadIdx.x;
  {
    int cl = t >> 2, nc = (t & 3) * 16;
    #pragma unroll
    for (int u = 0; u < 4; ++u) {
      float4 v = *(const float4*)&xp[(long)cl * 4096 + nc + u * 4];
      T[nc + u*4 + 0][cl] = v.x; T[nc + u*4 + 1][cl] = v.y;
      T[nc + u*4 + 2][cl] = v.z; T[nc + u*4 + 3][cl] = v.w;
    }
  }
  __syncthreads();
  {
    int nl = t >> 2, cc = (t & 3) * 16;
    u32 wv[8];
    #pragma unroll
    for (int j = 0; j < 8; ++j)
      wv[j] = (u32)f2bf(T[nl][cc + 2*j]) | ((u32)f2bf(T[nl][cc + 2*j + 1]) << 16);
    *(uint4*)&op[(long)nl * 256 + cc]     = make_uint4(wv[0], wv[1], wv[2], wv[3]);
    *(uint4*)&op[(long)nl * 256 + cc + 8] = make_uint4(wv[4], wv[5], wv[6], wv[7]);
  }
}

// ---------- Wq/Wk/Wv [512][256] f32 -> bf16 ----------
__global__ __launch_bounds__(256) void convert_w(
    const float* __restrict__ w0, const float* __restrict__ w1, const float* __restrict__ w2,
    u16* __restrict__ o0, u16* __restrict__ o1, u16* __restrict__ o2) {
  int gid = blockIdx.x * 256 + threadIdx.x;    // 24576 threads * 16 elems
  int which = gid >> 13;
  int off = (gid & 8191) * 16;
  const float* src = (which == 0) ? w0 : (which == 1) ? w1 : w2;
  u16* dst = (which == 0) ? o0 : (which == 1) ? o1 : o2;
  u32 wv[8];
  #pragma unroll
  for (int u = 0; u < 2; ++u) {
    float4 a = *(const float4*)&src[off + u*8];
    float4 b = *(const float4*)&src[off + u*8 + 4];
    wv[u*4+0] = (u32)f2bf(a.x) | ((u32)f2bf(a.y) << 16);
    wv[u*4+1] = (u32)f2bf(a.z) | ((u32)f2bf(a.w) << 16);
    wv[u*4+2] = (u32)f2bf(b.x) | ((u32)f2bf(b.y) << 16);
    wv[u*4+3] = (u32)f2bf(b.z) | ((u32)f2bf(b.w) << 16);
  }
  *(uint4*)&dst[off]     = make_uint4(wv[0], wv[1], wv[2], wv[3]);
  *(uint4*)&dst[off + 8] = make_uint4(wv[4], wv[5], wv[6], wv[7]);
}

// ---------- MFMA GEMM: C[m,n] = (sum_k A[m,k]B^T[n,k] + bias[m])*scale ----------
// A bf16 [M,K] k-contig; B bf16 [N=4096][K] k-contig. 128x128 tile, BK=64, 4 waves.
// OUT_MODE: 0 = bf16 [m][4096], 1 = bf16 transposed [n][512], 2 = f32 [m][4096]
template<int OUT_MODE>
__global__ __launch_bounds__(256) void mfma_gemm(
    const u16* __restrict__ A, long aBatch,
    const u16* __restrict__ B, long bBatch,
    const float* __restrict__ bias,
    void* __restrict__ Cv, long cBatch,
    int K, float scale)
{
  int b = blockIdx.z;
  A += (long)b * aBatch;
  B += (long)b * bBatch;
  int m0 = blockIdx.y * 128, n0 = blockIdx.x * 128;

  __shared__ u16 sm[16384];          // A tile [0,8192) elems, B tile [8192,16384)
  int t = threadIdx.x, w = t >> 6, l = t & 63;
  int lr = l & 15, lk = l >> 4;      // frag row / k-group
  int wr = w >> 1, wcq = w & 1;      // wave quadrant (2x2 of 64x64)

  f32x4 acc[4][4];
  #pragma unroll
  for (int i = 0; i < 4; ++i)
    #pragma unroll
    for (int j = 0; j < 4; ++j)
      acc[i][j] = (f32x4){0.f, 0.f, 0.f, 0.f};

  // staging constants: lane l covers row seg*8+(l>>3), source k-slot pre-swizzled
  int srow8 = l >> 3;
  int ksl = ((l & 7) ^ (l >> 3)) * 8;   // element offset; slot^ (row&7), row&7 == l>>3

  int nkt = K >> 6;
  for (int kt = 0; kt < nkt; ++kt) {
    int k0 = kt << 6;
    __syncthreads();
    #pragma unroll
    for (int i = 0; i < 4; ++i) {
      int seg = w * 4 + i;
      int row = seg * 8 + srow8;
      async16(&sm[seg * 512], A + (long)(m0 + row) * K + k0 + ksl);
    }
    #pragma unroll
    for (int i = 0; i < 4; ++i) {
      int seg = w * 4 + i;
      int row = seg * 8 + srow8;
      async16(&sm[8192 + seg * 512], B + (long)(n0 + row) * K + k0 + ksl);
    }
    __syncthreads();
    #pragma unroll
    for (int s = 0; s < 2; ++s) {
      bf16x8 af[4], bf[4];
      #pragma unroll
      for (int mi = 0; mi < 4; ++mi) {
        int row = wr * 64 + mi * 16 + lr;
        int slot = (s * 4 + lk) ^ (row & 7);
        af[mi] = *(const bf16x8*)&sm[row * 64 + slot * 8];
      }
      #pragma unroll
      for (int ni = 0; ni < 4; ++ni) {
        int row = wcq * 64 + ni * 16 + lr;
        int slot = (s * 4 + lk) ^ (row & 7);
        bf[ni] = *(const bf16x8*)&sm[8192 + row * 64 + slot * 8];
      }
      #pragma unroll
      for (int mi = 0; mi < 4; ++mi)
        #pragma unroll
        for (int ni = 0; ni < 4; ++ni)
          acc[mi][ni] = __builtin_amdgcn_mfma_f32_16x16x32_bf16(af[mi], bf[ni], acc[mi][ni], 0, 0, 0);
    }
  }

  // epilogue: C/D frag layout col=lane&15, row=(lane>>4)*4+reg
  if (OUT_MODE == 1) {
    u16* Cq = (u16*)Cv + (long)b * cBatch;
    #pragma unroll
    for (int mi = 0; mi < 4; ++mi) {
      int mb = m0 + wr * 64 + mi * 16 + lk * 4;
      float b0 = bias[mb], b1 = bias[mb+1], b2 = bias[mb+2], b3 = bias[mb+3];
      #pragma unroll
      for (int ni = 0; ni < 4; ++ni) {
        int n = n0 + wcq * 64 + ni * 16 + lr;
        f32x4 v = acc[mi][ni];
        ushort4 o;
        o.x = f2bf((v[0] + b0) * scale); o.y = f2bf((v[1] + b1) * scale);
        o.z = f2bf((v[2] + b2) * scale); o.w = f2bf((v[3] + b3) * scale);
        *(ushort4*)&Cq[(long)n * 512 + mb] = o;
      }
    }
  } else if (OUT_MODE == 0) {
    u16* Cb = (u16*)Cv + (long)b * cBatch;
    #pragma unroll
    for (int mi = 0; mi < 4; ++mi)
      #pragma unroll
      for (int r = 0; r < 4; ++r) {
        int m = m0 + wr * 64 + mi * 16 + lk * 4 + r;
        float bi = bias[m];
        #pragma unroll
        for (int ni = 0; ni < 4; ++ni) {
          int n = n0 + wcq * 64 + ni * 16 + lr;
          Cb[(long)m * NPOS + n] = f2bf((acc[mi][ni][r] + bi) * scale);
        }
      }
  } else {
    float* Cf = (float*)Cv + (long)b * cBatch;
    #pragma unroll
    for (int mi = 0; mi < 4; ++mi)
      #pragma unroll
      for (int r = 0; r < 4; ++r) {
        int m = m0 + wr * 64 + mi * 16 + lk * 4 + r;
        float bi = bias[m];
        #pragma unroll
        for (int ni = 0; ni < 4; ++ni) {
          int n = n0 + wcq * 64 + ni * 16 + lr;
          Cf[(long)m * NPOS + n] = acc[mi][ni][r] + bi;
        }
      }
  }
}

// ---------- softmax over n (4096) per row, in-place bf16 ----------
__global__ __launch_bounds__(256) void softmax_n(u16* __restrict__ kd) {
  long row = blockIdx.x;            // 16*512 rows
  u16* p = kd + row * NPOS;
  int tid = threadIdx.x;
  int lane = tid & 63, wid = tid >> 6;

  float v[16];
  uint4 r0 = *(const uint4*)(p + tid * 16);
  uint4 r1 = *(const uint4*)(p + tid * 16 + 8);
  unpack8(r0, v); unpack8(r1, v + 8);

  float mx = -1e30f;
  #pragma unroll
  for (int u = 0; u < 16; ++u) mx = fmaxf(mx, v[u]);
  #pragma unroll
  for (int off = 32; off > 0; off >>= 1) mx = fmaxf(mx, __shfl_xor(mx, off));
  __shared__ float smx[4], ssum[4];
  if (lane == 0) smx[wid] = mx;
  __syncthreads();
  mx = fmaxf(fmaxf(smx[0], smx[1]), fmaxf(smx[2], smx[3]));

  float s = 0.f;
  #pragma unroll
  for (int u = 0; u < 16; ++u) { v[u] = __expf(v[u] - mx); s += v[u]; }
  #pragma unroll
  for (int off = 32; off > 0; off >>= 1) s += __shfl_xor(s, off);
  if (lane == 0) ssum[wid] = s;
  __syncthreads();
  s = ssum[0] + ssum[1] + ssum[2] + ssum[3];
  float inv = 1.f / s;

  uint4 o0, o1;
  o0.x = (u32)f2bf(v[0]*inv)  | ((u32)f2bf(v[1]*inv)  << 16);
  o0.y = (u32)f2bf(v[2]*inv)  | ((u32)f2bf(v[3]*inv)  << 16);
  o0.z = (u32)f2bf(v[4]*inv)  | ((u32)f2bf(v[5]*inv)  << 16);
  o0.w = (u32)f2bf(v[6]*inv)  | ((u32)f2bf(v[7]*inv)  << 16);
  o1.x = (u32)f2bf(v[8]*inv)  | ((u32)f2bf(v[9]*inv)  << 16);
  o1.y = (u32)f2bf(v[10]*inv) | ((u32)f2bf(v[11]*inv) << 16);
  o1.z = (u32)f2bf(v[12]*inv) | ((u32)f2bf(v[13]*inv) << 16);
  o1.w = (u32)f2bf(v[14]*inv) | ((u32)f2bf(v[15]*inv) << 16);
  *(uint4*)(p + tid * 16) = o0;
  *(uint4*)(p + tid * 16 + 8) = o1;
}

// ---------- ctx partial: ctxp[ns][bh][d][e] = sum_{n in 256-chunk} ksm[d,n]*v[e,n] ----------
// 1 wave per block, MFMA frags straight from global (B^T pattern, n is K-dim).
__global__ __launch_bounds__(64) void ctx_mfma(
    const u16* __restrict__ ksm, const u16* __restrict__ vv, float* __restrict__ ctxp) {
  int ns = blockIdx.x;   // 16
  int bh = blockIdx.y;   // 128
  const u16* kp = ksm + (long)bh * 64 * NPOS + ns * 256;
  const u16* vp = vv  + (long)bh * 64 * NPOS + ns * 256;
  int l = threadIdx.x;
  int lr = l & 15, lk = l >> 4;
  f32x4 acc[4][4];
  #pragma unroll
  for (int i = 0; i < 4; ++i)
    #pragma unroll
    for (int j = 0; j < 4; ++j)
      acc[i][j] = (f32x4){0.f, 0.f, 0.f, 0.f};

  #pragma unroll 2
  for (int s = 0; s < 8; ++s) {
    int nn = s * 32 + lk * 8;
    bf16x8 a[4], bb[4];
    #pragma unroll
    for (int mi = 0; mi < 4; ++mi)
      a[mi] = *(const bf16x8*)(kp + (long)(mi * 16 + lr) * NPOS + nn);
    #pragma unroll
    for (int ni = 0; ni < 4; ++ni)
      bb[ni] = *(const bf16x8*)(vp + (long)(ni * 16 + lr) * NPOS + nn);
    #pragma unroll
    for (int mi = 0; mi < 4; ++mi)
      #pragma unroll
      for (int ni = 0; ni < 4; ++ni)
        acc[mi][ni] = __builtin_amdgcn_mfma_f32_16x16x32_bf16(a[mi], bb[ni], acc[mi][ni], 0, 0, 0);
  }
  float* cp = ctxp + ((long)ns * 128 + bh) * 4096;
  #pragma unroll
  for (int mi = 0; mi < 4; ++mi)
    #pragma unroll
    for (int ni = 0; ni < 4; ++ni)
      #pragma unroll
      for (int r = 0; r < 4; ++r)
        cp[(mi * 16 + lk * 4 + r) * 64 + ni * 16 + lr] = acc[mi][ni][r];
}

// ---------- Wc[b,co,h*64+d] = sum_e Wo[co,h*64+e] * ctx[b,h,d,e]  (bf16 out) ----------
__global__ __launch_bounds__(256) void wc_kernel(
    const float* __restrict__ ctxp, const float* __restrict__ Wo, u16* __restrict__ Wc)
{
  int bh = blockIdx.x;            // 128
  int bb = bh >> 3, h = bh & 7;
  __shared__ float Cs[64][65];    // [d][e] summed ctx
  __shared__ float Ws[64][65];    // [co(64-chunk)][e]
  int tid = threadIdx.x, tx = tid & 15, ty = tid >> 4;

  {
    int row = tid >> 2;
    int ec  = (tid & 3) << 4;
    #pragma unroll
    for (int u = 0; u < 4; ++u) {
      float4 s = make_float4(0, 0, 0, 0);
      #pragma unroll
      for (int si = 0; si < 16; ++si) {
        float4 tv = *(const float4*)&ctxp[(((long)si * 128 + bh) * 64 + row) * 64 + ec + u * 4];
        s.x += tv.x; s.y += tv.y; s.z += tv.z; s.w += tv.w;
      }
      Cs[row][ec + u*4 + 0] = s.x; Cs[row][ec + u*4 + 1] = s.y;
      Cs[row][ec + u*4 + 2] = s.z; Cs[row][ec + u*4 + 3] = s.w;
    }
  }
  for (int cc = 0; cc < 4; ++cc) {
    __syncthreads();
    {
      int row = tid >> 2;
      int ec  = (tid & 3) << 4;
      #pragma unroll
      for (int u = 0; u < 4; ++u) {
        float4 wv = *(const float4*)&Wo[(long)(cc * 64 + row) * 512 + h * 64 + ec + u * 4];
        Ws[row][ec + u*4 + 0] = wv.x; Ws[row][ec + u*4 + 1] = wv.y;
        Ws[row][ec + u*4 + 2] = wv.z; Ws[row][ec + u*4 + 3] = wv.w;
      }
    }
    __syncthreads();
    float acc[4][4] = {};
    #pragma unroll 8
    for (int e = 0; e < 64; ++e) {
      float a[4], b[4];
      #pragma unroll
      for (int i = 0; i < 4; ++i) a[i] = Ws[(ty << 2) + i][e];
      #pragma unroll
      for (int j = 0; j < 4; ++j) b[j] = Cs[(tx << 2) + j][e];
      #pragma unroll
      for (int i = 0; i < 4; ++i)
        #pragma unroll
        for (int j = 0; j < 4; ++j)
          acc[i][j] += a[i] * b[j];
    }
    #pragma unroll
    for (int i = 0; i < 4; ++i) {
      int co = cc * 64 + (ty << 2) + i;
      ushort4 o;
      o.x = f2bf(acc[i][0]); o.y = f2bf(acc[i][1]);
      o.z = f2bf(acc[i][2]); o.w = f2bf(acc[i][3]);
      *(ushort4*)&Wc[((long)bb * 256 + co) * 512 + h * 64 + (tx << 2)] = o;
    }
  }
}

// ---------- softmax over d (64 contiguous) per (b,n,h), in-place on qT ----------
__global__ __launch_bounds__(256) void softmax_d_t(u16* __restrict__ qT) {
  long gid = (long)blockIdx.x * 256 + threadIdx.x;   // 16*4096*8 units
  u16* p = qT + gid * 64;
  float v[64];
  #pragma unroll
  for (int u = 0; u < 8; ++u) {
    uint4 r = *(const uint4*)(p + u * 8);
    unpack8(r, v + u * 8);
  }
  float mx = -1e30f;
  #pragma unroll
  for (int d = 0; d < 64; ++d) mx = fmaxf(mx, v[d]);
  float s = 0.f;
  #pragma unroll
  for (int d = 0; d < 64; ++d) { v[d] = __expf(v[d] - mx); s += v[d]; }
  float inv = 1.f / s;
  #pragma unroll
  for (int u = 0; u < 8; ++u) {
    uint4 o;
    o.x = (u32)f2bf(v[u*8+0]*inv) | ((u32)f2bf(v[u*8+1]*inv) << 16);
    o.y = (u32)f2bf(v[u*8+2]*inv) | ((u32)f2bf(v[u*8+3]*inv) << 16);
    o.z = (u32)f2bf(v[u*8+4]*inv) | ((u32)f2bf(v[u*8+5]*inv) << 16);
    o.w = (u32)f2bf(v[u*8+6]*inv) | ((u32)f2bf(v[u*8+7]*inv) << 16);
    *(uint4*)(p + u * 8) = o;
  }
}

// ---------- launch ----------
extern "C" void kernel_launch(void* const* d_in, const int* in_sizes, int n_in,
                              void* d_out, int out_size, void* d_ws, size_t ws_size,
                              hipStream_t stream) {
  (void)in_sizes; (void)n_in; (void)out_size; (void)ws_size;
  const float* x  = (const float*)d_in[0];
  const float* Wq = (const float*)d_in[1];
  const float* bq = (const float*)d_in[2];
  const float* Wk = (const float*)d_in[3];
  const float* bk = (const float*)d_in[4];
  const float* Wv = (const float*)d_in[5];
  const float* bv = (const float*)d_in[6];
  const float* Wo = (const float*)d_in[7];
  const float* bo = (const float*)d_in[8];
  float* out = (float*)d_out;

  char* ws = (char*)d_ws;
  u16*   xT   = (u16*)(ws);                  // 32MB [16][4096][256]  (dead after projections)
  float* ctxp = (float*)(ws);                // 32MB [16][128][64][64] aliases xT
  u16*   qT   = (u16*)(ws + 33554432L);      // 64MB [16][4096][512]
  u16*   kb   = (u16*)(ws + 100663296L);     // 64MB [16][512][4096]
  u16*   Wcb  = (u16*)(ws + 167772160L);     // 4MB  [16][256][512] bf16
  u16*   Wqb  = (u16*)(ws + 171966464L);     // 256KB
  u16*   Wkb  = (u16*)(ws + 172228608L);     // 256KB
  u16*   Wvb  = (u16*)(ws + 172490752L);     // 256KB
  u16*   vb   = (u16*)d_out;                 // 64MB scratch; dead before final GEMM writes

  dim3 blk(256);
  long bBx = (long)NPOS * 256;     // xT batch stride
  long cBqkv = (long)512 * NPOS;   // k/v batch stride
  long cBqT = (long)NPOS * 512;    // qT batch stride

  hipLaunchKernelGGL(transpose_x, dim3(64, 4, NB), blk, 0, stream, x, xT);
  hipLaunchKernelGGL(convert_w, dim3(96), blk, 0, stream, Wq, Wk, Wv, Wqb, Wkb, Wvb);

  // projections: M=512, K=256, N=4096
  hipLaunchKernelGGL(HIP_KERNEL_NAME(mfma_gemm<1>), dim3(32, 4, NB), blk, 0, stream,
                     Wqb, 0L, xT, bBx, bq, (void*)qT, cBqT, 256, QK_SCALE);
  hipLaunchKernelGGL(HIP_KERNEL_NAME(mfma_gemm<0>), dim3(32, 4, NB), blk, 0, stream,
                     Wkb, 0L, xT, bBx, bk, (void*)kb, cBqkv, 256, QK_SCALE);
  hipLaunchKernelGGL(HIP_KERNEL_NAME(mfma_gemm<0>), dim3(32, 4, NB), blk, 0, stream,
                     Wvb, 0L, xT, bBx, bv, (void*)vb, cBqkv, 256, 1.0f);

  hipLaunchKernelGGL(softmax_n, dim3(NB * 512), blk, 0, stream, kb);
  hipLaunchKernelGGL(ctx_mfma, dim3(16, NB * NHEADS), dim3(64), 0, stream, kb, vb, ctxp);
  hipLaunchKernelGGL(wc_kernel, dim3(NB * NHEADS), blk, 0, stream, ctxp, Wo, Wcb);
  hipLaunchKernelGGL(softmax_d_t, dim3(NB * NPOS * NHEADS / 256), blk, 0, stream, qT);

  // final: out[b] = Wc[b] @ q_sm  (M=256, K=512, N=4096)
  hipLaunchKernelGGL(HIP_KERNEL_NAME(mfma_gemm<2>), dim3(32, 2, NB), blk, 0, stream,
                     Wcb, (long)256 * 512, qT, cBqT, bo, (void*)out, (long)256 * NPOS,
                     512, 1.0f);
}

// Round 3
// 306.174 us; speedup vs baseline: 3.7622x; 1.1738x over previous
//
#include <hip/hip_runtime.h>
#include <hip/hip_bf16.h>

typedef unsigned short u16;
typedef unsigned int u32;
typedef __attribute__((ext_vector_type(8))) short bf16x8;
typedef __attribute__((ext_vector_type(4))) float f32x4;

#define NB 16
#define NPOS 4096
#define QK_SCALE 0.35355339059327373f

// ---------- bf16 helpers ----------
__device__ __forceinline__ float bf2f(u32 u) {
  union { u32 i; float f; } x; x.i = u << 16; return x.f;
}
__device__ __forceinline__ u16 f2bf(float f) {
  union { float f; u32 i; } x; x.f = f;
  u32 r = x.i + 0x7fffu + ((x.i >> 16) & 1u);
  return (u16)(r >> 16);
}

// async global->LDS, 16B per lane; lds dst is wave-uniform base (+lane*16 by HW)
__device__ __forceinline__ void async16(u16* ldst, const u16* gsrc) {
  __builtin_amdgcn_global_load_lds(
      (const __attribute__((address_space(1))) unsigned int*)gsrc,
      (__attribute__((address_space(3))) unsigned int*)ldst, 16, 0, 0);
}

// ---------- x: [16][256][4096] f32  ->  xT: [16][4096][256] bf16 ----------
__global__ __launch_bounds__(256) void transpose_x(const float* __restrict__ x,
                                                   u16* __restrict__ xT) {
  int b = blockIdx.z;
  int c0 = blockIdx.y * 64;
  int n0 = blockIdx.x * 64;
  const float* xp = x + ((long)b * 256 + c0) * 4096 + n0;
  u16* op = xT + ((long)b * 4096 + n0) * 256 + c0;
  __shared__ float T[64][65];
  int t = threadIdx.x;
  {
    int cl = t >> 2, nc = (t & 3) * 16;
    #pragma unroll
    for (int u = 0; u < 4; ++u) {
      float4 v = *(const float4*)&xp[(long)cl * 4096 + nc + u * 4];
      T[nc + u*4 + 0][cl] = v.x; T[nc + u*4 + 1][cl] = v.y;
      T[nc + u*4 + 2][cl] = v.z; T[nc + u*4 + 3][cl] = v.w;
    }
  }
  __syncthreads();
  {
    int nl = t >> 2, cc = (t & 3) * 16;
    u32 wv[8];
    #pragma unroll
    for (int j = 0; j < 8; ++j)
      wv[j] = (u32)f2bf(T[nl][cc + 2*j]) | ((u32)f2bf(T[nl][cc + 2*j + 1]) << 16);
    *(uint4*)&op[(long)nl * 256 + cc]     = make_uint4(wv[0], wv[1], wv[2], wv[3]);
    *(uint4*)&op[(long)nl * 256 + cc + 8] = make_uint4(wv[4], wv[5], wv[6], wv[7]);
  }
}

// ---------- stack Wq/Wk/Wv -> bf16 [1536][256] with scale baked; bias f32 [1536] ----------
__global__ __launch_bounds__(256) void convert_wqkv(
    const float* __restrict__ Wq, const float* __restrict__ Wk, const float* __restrict__ Wv,
    const float* __restrict__ bq, const float* __restrict__ bk, const float* __restrict__ bv,
    u16* __restrict__ W, float* __restrict__ bias)
{
  if (blockIdx.x < 96) {
    int gid = blockIdx.x * 256 + threadIdx.x;    // 24576 threads * 16 elems
    int which = gid >> 13;
    int off = (gid & 8191) * 16;
    const float* src = which == 0 ? Wq : which == 1 ? Wk : Wv;
    float scl = which == 2 ? 1.0f : QK_SCALE;
    u16* dst = W + which * 131072;
    u32 wv_[8];
    #pragma unroll
    for (int u = 0; u < 4; ++u) {
      float4 a = *(const float4*)&src[off + u * 4];
      wv_[u*2+0] = (u32)f2bf(a.x*scl) | ((u32)f2bf(a.y*scl) << 16);
      wv_[u*2+1] = (u32)f2bf(a.z*scl) | ((u32)f2bf(a.w*scl) << 16);
    }
    *(uint4*)&dst[off]     = make_uint4(wv_[0], wv_[1], wv_[2], wv_[3]);
    *(uint4*)&dst[off + 8] = make_uint4(wv_[4], wv_[5], wv_[6], wv_[7]);
  } else {
    int t = threadIdx.x;
    #pragma unroll
    for (int u = 0; u < 6; ++u) {
      int i = t * 6 + u;
      if (i < 1536) {
        int which = i >> 9, r = i & 511;
        float v = which == 0 ? bq[r] : which == 1 ? bk[r] : bv[r];
        bias[i] = which == 2 ? v : v * QK_SCALE;
      }
    }
  }
}

// ---------- fused QKV projection, 2-phase pipelined, fused epilogues ----------
// A = Wqkv [1536][256] bf16 k-contig; B = xT [4096][256] bf16 k-contig (per batch).
// mb 0-3: q -> softmax-over-d fused, store qT[n][512] bf16
// mb 4-7: k -> store exp(k) bf16 [512][4096]
// mb 8-11: v -> store bf16 [512][4096]
__global__ __launch_bounds__(256) void proj_qkv(
    const u16* __restrict__ W, const float* __restrict__ bias,
    const u16* __restrict__ xT, u16* __restrict__ qT,
    u16* __restrict__ kx, u16* __restrict__ vb)
{
  int b = blockIdx.z;
  const u16* Bm = xT + (long)b * (4096L * 256);
  int mb = blockIdx.y;
  int m0 = mb * 128, n0 = blockIdx.x * 128;

  __shared__ u16 sm[32768];   // 2 buffers x (A 8192 + B 8192) u16
  int t = threadIdx.x, w = t >> 6, l = t & 63;
  int lr = l & 15, lk = l >> 4;
  int wr = w >> 1, wcq = w & 1;
  int srow8 = l >> 3;
  int ksl = ((l & 7) ^ srow8) * 8;   // pre-swizzled source k-slot

  f32x4 acc[4][4];
  #pragma unroll
  for (int i = 0; i < 4; ++i)
    #pragma unroll
    for (int j = 0; j < 4; ++j) acc[i][j] = (f32x4){0.f, 0.f, 0.f, 0.f};

#define STAGE_P(buf, kt) { \
    u16* base_ = sm + (buf) * 16384; \
    int k0_ = (kt) * 64; \
    _Pragma("unroll") \
    for (int i_ = 0; i_ < 4; ++i_) { \
      int seg_ = w * 4 + i_; \
      int row_ = seg_ * 8 + srow8; \
      async16(base_ + seg_ * 512, W + (long)(m0 + row_) * 256 + k0_ + ksl); \
      async16(base_ + 8192 + seg_ * 512, Bm + (long)(n0 + row_) * 256 + k0_ + ksl); \
    } }

#define COMPUTE_P(buf) { \
    const u16* base_ = sm + (buf) * 16384; \
    _Pragma("unroll") \
    for (int s_ = 0; s_ < 2; ++s_) { \
      bf16x8 af_[4], bf_[4]; \
      _Pragma("unroll") \
      for (int mi_ = 0; mi_ < 4; ++mi_) { \
        int row_ = wr * 64 + mi_ * 16 + lr; \
        int slot_ = (s_ * 4 + lk) ^ (row_ & 7); \
        af_[mi_] = *(const bf16x8*)&base_[row_ * 64 + slot_ * 8]; \
      } \
      _Pragma("unroll") \
      for (int ni_ = 0; ni_ < 4; ++ni_) { \
        int row_ = wcq * 64 + ni_ * 16 + lr; \
        int slot_ = (s_ * 4 + lk) ^ (row_ & 7); \
        bf_[ni_] = *(const bf16x8*)&base_[8192 + row_ * 64 + slot_ * 8]; \
      } \
      _Pragma("unroll") \
      for (int mi_ = 0; mi_ < 4; ++mi_) \
        _Pragma("unroll") \
        for (int ni_ = 0; ni_ < 4; ++ni_) \
          acc[mi_][ni_] = __builtin_amdgcn_mfma_f32_16x16x32_bf16(af_[mi_], bf_[ni_], acc[mi_][ni_], 0, 0, 0); \
    } }

#define WAITBAR asm volatile("s_waitcnt vmcnt(0)" ::: "memory"); __builtin_amdgcn_s_barrier();

  // 2-phase: stage(next) -> compute(cur) -> vmcnt(0)+barrier (loads hidden under MFMA)
  STAGE_P(0, 0)
  WAITBAR
  STAGE_P(1, 1)
  COMPUTE_P(0)
  WAITBAR
  STAGE_P(0, 2)
  COMPUTE_P(1)
  WAITBAR
  STAGE_P(1, 3)
  COMPUTE_P(0)
  WAITBAR
  COMPUTE_P(1)

  int mbase = m0 + wr * 64;       // multiple of 64 (head-aligned for q)
  int nbase = n0 + wcq * 64;

  if (mb < 4) {
    // Q: fused softmax over d (wave's 64-row quadrant == one head)
    float bv_[4][4];
    #pragma unroll
    for (int mi = 0; mi < 4; ++mi)
      #pragma unroll
      for (int r = 0; r < 4; ++r) bv_[mi][r] = bias[mbase + mi * 16 + lk * 4 + r];
    u16* qp = qT + (long)b * (4096L * 512);
    #pragma unroll
    for (int ni = 0; ni < 4; ++ni) {
      float ssum = 0.f;
      #pragma unroll
      for (int mi = 0; mi < 4; ++mi)
        #pragma unroll
        for (int r = 0; r < 4; ++r) {
          float e = __expf(acc[mi][ni][r] + bv_[mi][r]);
          acc[mi][ni][r] = e; ssum += e;
        }
      ssum += __shfl_xor(ssum, 16);
      ssum += __shfl_xor(ssum, 32);
      float inv = 1.f / ssum;
      int n = nbase + ni * 16 + lr;
      #pragma unroll
      for (int mi = 0; mi < 4; ++mi) {
        ushort4 o;
        o.x = f2bf(acc[mi][ni][0] * inv); o.y = f2bf(acc[mi][ni][1] * inv);
        o.z = f2bf(acc[mi][ni][2] * inv); o.w = f2bf(acc[mi][ni][3] * inv);
        *(ushort4*)&qp[(long)n * 512 + mbase + mi * 16 + lk * 4] = o;
      }
    }
  } else if (mb < 8) {
    // K: store exp(logit) unnormalized
    u16* kp = kx + (long)b * (512L * 4096) + (long)(mbase - 512) * 4096;
    #pragma unroll
    for (int mi = 0; mi < 4; ++mi)
      #pragma unroll
      for (int r = 0; r < 4; ++r) {
        int mr = mi * 16 + lk * 4 + r;
        float bi = bias[mbase + mr];
        #pragma unroll
        for (int ni = 0; ni < 4; ++ni) {
          int n = nbase + ni * 16 + lr;
          kp[(long)mr * 4096 + n] = f2bf(__expf(acc[mi][ni][r] + bi));
        }
      }
  } else {
    // V: plain
    u16* vp = vb + (long)b * (512L * 4096) + (long)(mbase - 1024) * 4096;
    #pragma unroll
    for (int mi = 0; mi < 4; ++mi)
      #pragma unroll
      for (int r = 0; r < 4; ++r) {
        int mr = mi * 16 + lk * 4 + r;
        float bi = bias[mbase + mr];
        #pragma unroll
        for (int ni = 0; ni < 4; ++ni) {
          int n = nbase + ni * 16 + lr;
          vp[(long)mr * 4096 + n] = f2bf(acc[mi][ni][r] + bi);
        }
      }
  }
#undef STAGE_P
#undef COMPUTE_P
}

// ---------- ctx partials: Sp[ns][bh][d][e] = sum_n expk[d,n] v[e,n]; Zp = sum_n expk[d,n] ----------
__global__ __launch_bounds__(64) void ctx_mfma(
    const u16* __restrict__ kx, const u16* __restrict__ vv,
    float* __restrict__ Sp, float* __restrict__ Zp)
{
  int ns = blockIdx.x;   // 16 chunks of 256
  int bh = blockIdx.y;   // 128
  const u16* kp = kx + (long)bh * 64 * NPOS + ns * 256;
  const u16* vp = vv + (long)bh * 64 * NPOS + ns * 256;
  int l = threadIdx.x, lr = l & 15, lk = l >> 4;
  f32x4 acc[4][4]; f32x4 az[4];
  #pragma unroll
  for (int i = 0; i < 4; ++i) {
    az[i] = (f32x4){0.f, 0.f, 0.f, 0.f};
    #pragma unroll
    for (int j = 0; j < 4; ++j) acc[i][j] = (f32x4){0.f, 0.f, 0.f, 0.f};
  }
  bf16x8 ones;
  #pragma unroll
  for (int j = 0; j < 8; ++j) ones[j] = (short)0x3F80;

  #pragma unroll 2
  for (int s = 0; s < 8; ++s) {
    int nn = s * 32 + lk * 8;
    bf16x8 a[4], bb[4];
    #pragma unroll
    for (int mi = 0; mi < 4; ++mi)
      a[mi] = *(const bf16x8*)(kp + (long)(mi * 16 + lr) * NPOS + nn);
    #pragma unroll
    for (int ni = 0; ni < 4; ++ni)
      bb[ni] = *(const bf16x8*)(vp + (long)(ni * 16 + lr) * NPOS + nn);
    #pragma unroll
    for (int mi = 0; mi < 4; ++mi)
      az[mi] = __builtin_amdgcn_mfma_f32_16x16x32_bf16(a[mi], ones, az[mi], 0, 0, 0);
    #pragma unroll
    for (int mi = 0; mi < 4; ++mi)
      #pragma unroll
      for (int ni = 0; ni < 4; ++ni)
        acc[mi][ni] = __builtin_amdgcn_mfma_f32_16x16x32_bf16(a[mi], bb[ni], acc[mi][ni], 0, 0, 0);
  }
  float* sp = Sp + ((long)ns * 128 + bh) * 4096;
  #pragma unroll
  for (int mi = 0; mi < 4; ++mi)
    #pragma unroll
    for (int ni = 0; ni < 4; ++ni)
      #pragma unroll
      for (int r = 0; r < 4; ++r)
        sp[(mi * 16 + lk * 4 + r) * 64 + ni * 16 + lr] = acc[mi][ni][r];
  if (lr == 0) {
    float* zp = Zp + ((long)ns * 128 + bh) * 64;
    #pragma unroll
    for (int mi = 0; mi < 4; ++mi)
      #pragma unroll
      for (int r = 0; r < 4; ++r)
        zp[mi * 16 + lk * 4 + r] = az[mi][r];
  }
}

// ---------- Wc[b,co,h*64+d] = sum_e Wo[co,h*64+e] * (S[d,e]/Z[d])  (bf16 out) ----------
__global__ __launch_bounds__(256) void wc_kernel(
    const float* __restrict__ Sp, const float* __restrict__ Zp,
    const float* __restrict__ Wo, u16* __restrict__ Wc)
{
  int bh = blockIdx.x;            // 128
  int bb = bh >> 3, h = bh & 7;
  __shared__ float Cs[64][65];    // normalized ctx [d][e]
  __shared__ float Ws[64][65];    // Wo chunk [co][e]
  int tid = threadIdx.x, tx = tid & 15, ty = tid >> 4;

  {
    int row = tid >> 2;
    int ec  = (tid & 3) << 4;
    float Zr = 0.f;
    #pragma unroll
    for (int si = 0; si < 16; ++si) Zr += Zp[((long)si * 128 + bh) * 64 + row];
    float invZ = 1.f / Zr;
    #pragma unroll
    for (int u = 0; u < 4; ++u) {
      float4 s = make_float4(0, 0, 0, 0);
      #pragma unroll
      for (int si = 0; si < 16; ++si) {
        float4 tv = *(const float4*)&Sp[(((long)si * 128 + bh) * 64 + row) * 64 + ec + u * 4];
        s.x += tv.x; s.y += tv.y; s.z += tv.z; s.w += tv.w;
      }
      Cs[row][ec + u*4 + 0] = s.x * invZ; Cs[row][ec + u*4 + 1] = s.y * invZ;
      Cs[row][ec + u*4 + 2] = s.z * invZ; Cs[row][ec + u*4 + 3] = s.w * invZ;
    }
  }
  for (int cc = 0; cc < 4; ++cc) {
    __syncthreads();
    {
      int row = tid >> 2;
      int ec  = (tid & 3) << 4;
      #pragma unroll
      for (int u = 0; u < 4; ++u) {
        float4 wv = *(const float4*)&Wo[(long)(cc * 64 + row) * 512 + h * 64 + ec + u * 4];
        Ws[row][ec + u*4 + 0] = wv.x; Ws[row][ec + u*4 + 1] = wv.y;
        Ws[row][ec + u*4 + 2] = wv.z; Ws[row][ec + u*4 + 3] = wv.w;
      }
    }
    __syncthreads();
    float acc[4][4] = {};
    #pragma unroll 8
    for (int e = 0; e < 64; ++e) {
      float a[4], b[4];
      #pragma unroll
      for (int i = 0; i < 4; ++i) a[i] = Ws[(ty << 2) + i][e];
      #pragma unroll
      for (int j = 0; j < 4; ++j) b[j] = Cs[(tx << 2) + j][e];
      #pragma unroll
      for (int i = 0; i < 4; ++i)
        #pragma unroll
        for (int j = 0; j < 4; ++j)
          acc[i][j] += a[i] * b[j];
    }
    #pragma unroll
    for (int i = 0; i < 4; ++i) {
      int co = cc * 64 + (ty << 2) + i;
      ushort4 o;
      o.x = f2bf(acc[i][0]); o.y = f2bf(acc[i][1]);
      o.z = f2bf(acc[i][2]); o.w = f2bf(acc[i][3]);
      *(ushort4*)&Wc[((long)bb * 256 + co) * 512 + h * 64 + (tx << 2)] = o;
    }
  }
}

// ---------- final: out[b] = Wc[b] @ qT[b]^T + bo, f32 out, 2-phase pipelined ----------
__global__ __launch_bounds__(256) void final_gemm(
    const u16* __restrict__ Wc, const u16* __restrict__ qTg,
    const float* __restrict__ bo, float* __restrict__ out)
{
  int b = blockIdx.z;
  const u16* A = Wc + (long)b * (256L * 512);
  const u16* Bm = qTg + (long)b * (4096L * 512);
  int m0 = blockIdx.y * 128, n0 = blockIdx.x * 128;

  __shared__ u16 sm[32768];
  int t = threadIdx.x, w = t >> 6, l = t & 63;
  int lr = l & 15, lk = l >> 4;
  int wr = w >> 1, wcq = w & 1;
  int srow8 = l >> 3;
  int ksl = ((l & 7) ^ srow8) * 8;

  f32x4 acc[4][4];
  #pragma unroll
  for (int i = 0; i < 4; ++i)
    #pragma unroll
    for (int j = 0; j < 4; ++j) acc[i][j] = (f32x4){0.f, 0.f, 0.f, 0.f};

#define STAGE_F(buf, kt) { \
    u16* base_ = sm + (buf) * 16384; \
    int k0_ = (kt) * 64; \
    _Pragma("unroll") \
    for (int i_ = 0; i_ < 4; ++i_) { \
      int seg_ = w * 4 + i_; \
      int row_ = seg_ * 8 + srow8; \
      async16(base_ + seg_ * 512, A + (long)(m0 + row_) * 512 + k0_ + ksl); \
      async16(base_ + 8192 + seg_ * 512, Bm + (long)(n0 + row_) * 512 + k0_ + ksl); \
    } }

#define COMPUTE_F(buf) { \
    const u16* base_ = sm + (buf) * 16384; \
    _Pragma("unroll") \
    for (int s_ = 0; s_ < 2; ++s_) { \
      bf16x8 af_[4], bf_[4]; \
      _Pragma("unroll") \
      for (int mi_ = 0; mi_ < 4; ++mi_) { \
        int row_ = wr * 64 + mi_ * 16 + lr; \
        int slot_ = (s_ * 4 + lk) ^ (row_ & 7); \
        af_[mi_] = *(const bf16x8*)&base_[row_ * 64 + slot_ * 8]; \
      } \
      _Pragma("unroll") \
      for (int ni_ = 0; ni_ < 4; ++ni_) { \
        int row_ = wcq * 64 + ni_ * 16 + lr; \
        int slot_ = (s_ * 4 + lk) ^ (row_ & 7); \
        bf_[ni_] = *(const bf16x8*)&base_[8192 + row_ * 64 + slot_ * 8]; \
      } \
      _Pragma("unroll") \
      for (int mi_ = 0; mi_ < 4; ++mi_) \
        _Pragma("unroll") \
        for (int ni_ = 0; ni_ < 4; ++ni_) \
          acc[mi_][ni_] = __builtin_amdgcn_mfma_f32_16x16x32_bf16(af_[mi_], bf_[ni_], acc[mi_][ni_], 0, 0, 0); \
    } }

  STAGE_F(0, 0)
  WAITBAR
  #pragma unroll
  for (int kt = 0; kt < 8; ++kt) {
    if (kt < 7) {
      if ((kt & 1) == 0) { STAGE_F(1, kt + 1) } else { STAGE_F(0, kt + 1) }
    }
    if ((kt & 1) == 0) { COMPUTE_F(0) } else { COMPUTE_F(1) }
    if (kt < 7) { WAITBAR }
  }

  float* op = out + (long)b * (256L * 4096);
  int mbase = m0 + wr * 64;
  int nbase = n0 + wcq * 64;
  #pragma unroll
  for (int mi = 0; mi < 4; ++mi)
    #pragma unroll
    for (int r = 0; r < 4; ++r) {
      int m = mbase + mi * 16 + lk * 4 + r;
      float bi = bo[m];
      #pragma unroll
      for (int ni = 0; ni < 4; ++ni) {
        int n = nbase + ni * 16 + lr;
        op[(long)m * 4096 + n] = acc[mi][ni][r] + bi;
      }
    }
#undef STAGE_F
#undef COMPUTE_F
}

// ---------- launch ----------
extern "C" void kernel_launch(void* const* d_in, const int* in_sizes, int n_in,
                              void* d_out, int out_size, void* d_ws, size_t ws_size,
                              hipStream_t stream) {
  (void)in_sizes; (void)n_in; (void)out_size; (void)ws_size;
  const float* x  = (const float*)d_in[0];
  const float* Wq = (const float*)d_in[1];
  const float* bq = (const float*)d_in[2];
  const float* Wk = (const float*)d_in[3];
  const float* bk = (const float*)d_in[4];
  const float* Wv = (const float*)d_in[5];
  const float* bv = (const float*)d_in[6];
  const float* Wo = (const float*)d_in[7];
  const float* bo = (const float*)d_in[8];
  float* out = (float*)d_out;

  char* ws = (char*)d_ws;
  u16*   xT    = (u16*)(ws);                  // 32MB [16][4096][256]; dead after proj
  float* Sp    = (float*)(ws);                // 32MB [16][128][64][64] aliases xT
  u16*   qT    = (u16*)(ws + 33554432L);      // 64MB [16][4096][512]
  u16*   kx    = (u16*)(ws + 100663296L);     // 64MB [16][512][4096] exp(k)
  u16*   Wcb   = (u16*)(ws + 167772160L);     // 4MB  [16][256][512] bf16
  u16*   Wqkvb = (u16*)(ws + 171966464L);     // 768KB [1536][256] bf16
  float* bqkv  = (float*)(ws + 172752896L);   // 6KB  [1536]
  float* Zp    = (float*)(ws + 172759040L);   // 512KB [16][128][64]
  u16*   vb    = (u16*)d_out;                 // 64MB scratch; dead before final writes

  dim3 blk(256);
  hipLaunchKernelGGL(transpose_x, dim3(64, 4, NB), blk, 0, stream, x, xT);
  hipLaunchKernelGGL(convert_wqkv, dim3(97), blk, 0, stream, Wq, Wk, Wv, bq, bk, bv, Wqkvb, bqkv);
  hipLaunchKernelGGL(proj_qkv, dim3(32, 12, NB), blk, 0, stream, Wqkvb, bqkv, xT, qT, kx, vb);
  hipLaunchKernelGGL(ctx_mfma, dim3(16, 128), dim3(64), 0, stream, kx, vb, Sp, Zp);
  hipLaunchKernelGGL(wc_kernel, dim3(128), blk, 0, stream, Sp, Zp, Wo, Wcb);
  hipLaunchKernelGGL(final_gemm, dim3(32, 2, NB), blk, 0, stream, Wcb, qT, bo, out);
}

// Round 4
// 299.661 us; speedup vs baseline: 3.8440x; 1.0217x over previous
//
#include <hip/hip_runtime.h>
#include <hip/hip_bf16.h>

typedef unsigned short u16;
typedef unsigned int u32;
typedef __attribute__((ext_vector_type(8))) short bf16x8;
typedef __attribute__((ext_vector_type(4))) float f32x4;

#define NB 16
#define NPOS 4096
#define QK_SCALE 0.35355339059327373f

// ---------- bf16 helpers ----------
__device__ __forceinline__ float bf2f(u32 u) {
  union { u32 i; float f; } x; x.i = u << 16; return x.f;
}
__device__ __forceinline__ u16 f2bf(float f) {
  union { float f; u32 i; } x; x.f = f;
  u32 r = x.i + 0x7fffu + ((x.i >> 16) & 1u);
  return (u16)(r >> 16);
}

// async global->LDS, 16B per lane; lds dst is wave-uniform base (+lane*16 by HW)
__device__ __forceinline__ void async16(u16* ldst, const u16* gsrc) {
  __builtin_amdgcn_global_load_lds(
      (const __attribute__((address_space(1))) unsigned int*)gsrc,
      (__attribute__((address_space(3))) unsigned int*)ldst, 16, 0, 0);
}

#define VW8 asm volatile("s_waitcnt vmcnt(8)" ::: "memory");
#define VW0 asm volatile("s_waitcnt vmcnt(0)" ::: "memory");
#define BAR __builtin_amdgcn_s_barrier();

// ---------- x: [16][256][4096] f32  ->  xT: [16][4096][256] bf16 ----------
__global__ __launch_bounds__(256) void transpose_x(const float* __restrict__ x,
                                                   u16* __restrict__ xT) {
  int b = blockIdx.z;
  int c0 = blockIdx.y * 64;
  int n0 = blockIdx.x * 64;
  const float* xp = x + ((long)b * 256 + c0) * 4096 + n0;
  u16* op = xT + ((long)b * 4096 + n0) * 256 + c0;
  __shared__ float T[64][65];
  int t = threadIdx.x;
  {
    int cl = t >> 2, nc = (t & 3) * 16;
    #pragma unroll
    for (int u = 0; u < 4; ++u) {
      float4 v = *(const float4*)&xp[(long)cl * 4096 + nc + u * 4];
      T[nc + u*4 + 0][cl] = v.x; T[nc + u*4 + 1][cl] = v.y;
      T[nc + u*4 + 2][cl] = v.z; T[nc + u*4 + 3][cl] = v.w;
    }
  }
  __syncthreads();
  {
    int nl = t >> 2, cc = (t & 3) * 16;
    u32 wv[8];
    #pragma unroll
    for (int j = 0; j < 8; ++j)
      wv[j] = (u32)f2bf(T[nl][cc + 2*j]) | ((u32)f2bf(T[nl][cc + 2*j + 1]) << 16);
    *(uint4*)&op[(long)nl * 256 + cc]     = make_uint4(wv[0], wv[1], wv[2], wv[3]);
    *(uint4*)&op[(long)nl * 256 + cc + 8] = make_uint4(wv[4], wv[5], wv[6], wv[7]);
  }
}

// ---------- stack Wq/Wk/Wv -> bf16 [1536][256] with scale baked; bias f32 [1536] ----------
__global__ __launch_bounds__(256) void convert_wqkv(
    const float* __restrict__ Wq, const float* __restrict__ Wk, const float* __restrict__ Wv,
    const float* __restrict__ bq, const float* __restrict__ bk, const float* __restrict__ bv,
    u16* __restrict__ W, float* __restrict__ bias)
{
  if (blockIdx.x < 96) {
    int gid = blockIdx.x * 256 + threadIdx.x;
    int which = gid >> 13;
    int off = (gid & 8191) * 16;
    const float* src = which == 0 ? Wq : which == 1 ? Wk : Wv;
    float scl = which == 2 ? 1.0f : QK_SCALE;
    u16* dst = W + which * 131072;
    u32 wv_[8];
    #pragma unroll
    for (int u = 0; u < 4; ++u) {
      float4 a = *(const float4*)&src[off + u * 4];
      wv_[u*2+0] = (u32)f2bf(a.x*scl) | ((u32)f2bf(a.y*scl) << 16);
      wv_[u*2+1] = (u32)f2bf(a.z*scl) | ((u32)f2bf(a.w*scl) << 16);
    }
    *(uint4*)&dst[off]     = make_uint4(wv_[0], wv_[1], wv_[2], wv_[3]);
    *(uint4*)&dst[off + 8] = make_uint4(wv_[4], wv_[5], wv_[6], wv_[7]);
  } else {
    int t = threadIdx.x;
    #pragma unroll
    for (int u = 0; u < 6; ++u) {
      int i = t * 6 + u;
      if (i < 1536) {
        int which = i >> 9, r = i & 511;
        float v = which == 0 ? bq[r] : which == 1 ? bk[r] : bv[r];
        bias[i] = which == 2 ? v : v * QK_SCALE;
      }
    }
  }
}

// ---------- projection kernels, counted-vmcnt 2-deep pipeline ----------
// MODE 0: Q rows 0-511, mfma(W,x): lane holds 4 consecutive m -> softmax-d + qT[n][512]
// MODE 1: K/V rows 512-1535, mfma(x,W): lane holds 4 consecutive n -> ushort4 [m][4096]
template<int MODE>
__global__ __launch_bounds__(256) void proj_kern(
    const u16* __restrict__ W, const float* __restrict__ bias,
    const u16* __restrict__ xT, u16* __restrict__ qT,
    u16* __restrict__ kx, u16* __restrict__ vb)
{
  int b = blockIdx.z;
  const u16* Bm = xT + (long)b * (4096L * 256);
  int mb = blockIdx.y;
  int m0 = (MODE == 0 ? 0 : 512) + mb * 128;
  int n0 = blockIdx.x * 128;

  __shared__ u16 sm[32768];   // 2 buffers x (A 8192 + B 8192) u16
  int t = threadIdx.x, w = t >> 6, l = t & 63;
  int lr = l & 15, lk = l >> 4;
  int wr = w >> 1, wcq = w & 1;
  int srow8 = l >> 3;
  int ksl = ((l & 7) ^ srow8) * 8;   // pre-swizzled source k-slot

  f32x4 acc[4][4];
  #pragma unroll
  for (int i = 0; i < 4; ++i)
    #pragma unroll
    for (int j = 0; j < 4; ++j) acc[i][j] = (f32x4){0.f, 0.f, 0.f, 0.f};

#define STAGE_P(buf, kt) { \
    u16* base_ = sm + (buf) * 16384; \
    int k0_ = (kt) * 64; \
    _Pragma("unroll") \
    for (int i_ = 0; i_ < 4; ++i_) { \
      int seg_ = w * 4 + i_; \
      int row_ = seg_ * 8 + srow8; \
      async16(base_ + seg_ * 512, W + (long)(m0 + row_) * 256 + k0_ + ksl); \
      async16(base_ + 8192 + seg_ * 512, Bm + (long)(n0 + row_) * 256 + k0_ + ksl); \
    } }

#define COMPUTE_P(buf) { \
    const u16* base_ = sm + (buf) * 16384; \
    _Pragma("unroll") \
    for (int s_ = 0; s_ < 2; ++s_) { \
      bf16x8 af_[4], bf_[4]; \
      _Pragma("unroll") \
      for (int mi_ = 0; mi_ < 4; ++mi_) { \
        int row_ = wr * 64 + mi_ * 16 + lr; \
        int slot_ = (s_ * 4 + lk) ^ (row_ & 7); \
        af_[mi_] = *(const bf16x8*)&base_[row_ * 64 + slot_ * 8]; \
      } \
      _Pragma("unroll") \
      for (int ni_ = 0; ni_ < 4; ++ni_) { \
        int row_ = wcq * 64 + ni_ * 16 + lr; \
        int slot_ = (s_ * 4 + lk) ^ (row_ & 7); \
        bf_[ni_] = *(const bf16x8*)&base_[8192 + row_ * 64 + slot_ * 8]; \
      } \
      _Pragma("unroll") \
      for (int mi_ = 0; mi_ < 4; ++mi_) \
        _Pragma("unroll") \
        for (int ni_ = 0; ni_ < 4; ++ni_) \
          acc[mi_][ni_] = MODE == 0 \
            ? __builtin_amdgcn_mfma_f32_16x16x32_bf16(af_[mi_], bf_[ni_], acc[mi_][ni_], 0, 0, 0) \
            : __builtin_amdgcn_mfma_f32_16x16x32_bf16(bf_[ni_], af_[mi_], acc[mi_][ni_], 0, 0, 0); \
    } }

  // counted-vmcnt pipeline over 4 K-tiles: next tile's loads fly under MFMA
  STAGE_P(0, 0)
  STAGE_P(1, 1)
  VW8 BAR
  COMPUTE_P(0)
  BAR
  STAGE_P(0, 2)
  VW8 BAR
  COMPUTE_P(1)
  BAR
  STAGE_P(1, 3)
  VW8 BAR
  COMPUTE_P(0)
  BAR
  VW0 BAR
  COMPUTE_P(1)

  if (MODE == 0) {
    // Q: fused softmax over d (wave's 64-row quadrant == one head), store qT[n][512]
    int mbase = m0 + wr * 64;
    int nbase = n0 + wcq * 64;
    float bv_[4][4];
    #pragma unroll
    for (int mi = 0; mi < 4; ++mi)
      #pragma unroll
      for (int r = 0; r < 4; ++r) bv_[mi][r] = bias[mbase + mi * 16 + lk * 4 + r];
    u16* qp = qT + (long)b * (4096L * 512);
    #pragma unroll
    for (int ni = 0; ni < 4; ++ni) {
      float ssum = 0.f;
      #pragma unroll
      for (int mi = 0; mi < 4; ++mi)
        #pragma unroll
        for (int r = 0; r < 4; ++r) {
          float e = __expf(acc[mi][ni][r] + bv_[mi][r]);
          acc[mi][ni][r] = e; ssum += e;
        }
      ssum += __shfl_xor(ssum, 16);
      ssum += __shfl_xor(ssum, 32);
      float inv = 1.f / ssum;
      int n = nbase + ni * 16 + lr;
      #pragma unroll
      for (int mi = 0; mi < 4; ++mi) {
        ushort4 o;
        o.x = f2bf(acc[mi][ni][0] * inv); o.y = f2bf(acc[mi][ni][1] * inv);
        o.z = f2bf(acc[mi][ni][2] * inv); o.w = f2bf(acc[mi][ni][3] * inv);
        *(ushort4*)&qp[(long)n * 512 + mbase + mi * 16 + lk * 4] = o;
      }
    }
  } else {
    // K/V (swapped): acc[mi][ni] holds n = n0+wcq*64+ni*16+lk*4+r, m = m0+wr*64+mi*16+lr
    bool is_k = (mb < 4);
    u16* dst = is_k ? (kx + (long)b * (512L * 4096) - 512L * 4096)
                    : (vb + (long)b * (512L * 4096) - 1024L * 4096);
    #pragma unroll
    for (int mi = 0; mi < 4; ++mi) {
      int m = m0 + wr * 64 + mi * 16 + lr;
      float bi = bias[m];
      u16* rowp = dst + (long)m * 4096;
      #pragma unroll
      for (int ni = 0; ni < 4; ++ni) {
        int nb2 = n0 + wcq * 64 + ni * 16 + lk * 4;
        f32x4 v = acc[mi][ni];
        ushort4 o;
        if (is_k) {
          o.x = f2bf(__expf(v[0] + bi)); o.y = f2bf(__expf(v[1] + bi));
          o.z = f2bf(__expf(v[2] + bi)); o.w = f2bf(__expf(v[3] + bi));
        } else {
          o.x = f2bf(v[0] + bi); o.y = f2bf(v[1] + bi);
          o.z = f2bf(v[2] + bi); o.w = f2bf(v[3] + bi);
        }
        *(ushort4*)&rowp[nb2] = o;
      }
    }
  }
#undef STAGE_P
#undef COMPUTE_P
}

// ---------- ctx partials with register double-buffer prefetch ----------
// Sp[ns][bh][d][e] = sum_n expk[d,n] v[e,n]; Zp[ns][bh][d] = sum_n expk[d,n]
__global__ __launch_bounds__(64) void ctx_mfma(
    const u16* __restrict__ kx, const u16* __restrict__ vv,
    float* __restrict__ Sp, float* __restrict__ Zp)
{
  int ns = blockIdx.x;   // 16 chunks of 256
  int bh = blockIdx.y;   // 128
  const u16* kp = kx + (long)bh * 64 * NPOS + ns * 256;
  const u16* vp = vv + (long)bh * 64 * NPOS + ns * 256;
  int l = threadIdx.x, lr = l & 15, lk = l >> 4;
  f32x4 acc[4][4]; f32x4 az[4];
  #pragma unroll
  for (int i = 0; i < 4; ++i) {
    az[i] = (f32x4){0.f, 0.f, 0.f, 0.f};
    #pragma unroll
    for (int j = 0; j < 4; ++j) acc[i][j] = (f32x4){0.f, 0.f, 0.f, 0.f};
  }
  bf16x8 ones;
  #pragma unroll
  for (int j = 0; j < 8; ++j) ones[j] = (short)0x3F80;

#define CTX_LOAD(as, bs, s) { \
    int nn_ = (s) * 32 + lk * 8; \
    _Pragma("unroll") \
    for (int mi_ = 0; mi_ < 4; ++mi_) \
      as[mi_] = *(const bf16x8*)(kp + (long)(mi_ * 16 + lr) * NPOS + nn_); \
    _Pragma("unroll") \
    for (int ni_ = 0; ni_ < 4; ++ni_) \
      bs[ni_] = *(const bf16x8*)(vp + (long)(ni_ * 16 + lr) * NPOS + nn_); }

#define CTX_MF(as, bs) { \
    _Pragma("unroll") \
    for (int mi_ = 0; mi_ < 4; ++mi_) \
      az[mi_] = __builtin_amdgcn_mfma_f32_16x16x32_bf16(as[mi_], ones, az[mi_], 0, 0, 0); \
    _Pragma("unroll") \
    for (int mi_ = 0; mi_ < 4; ++mi_) \
      _Pragma("unroll") \
      for (int ni_ = 0; ni_ < 4; ++ni_) \
        acc[mi_][ni_] = __builtin_amdgcn_mfma_f32_16x16x32_bf16(as[mi_], bs[ni_], acc[mi_][ni_], 0, 0, 0); }

  bf16x8 a0[4], b0[4], a1[4], b1[4];
  CTX_LOAD(a0, b0, 0)
  #pragma unroll
  for (int s = 0; s < 8; s += 2) {
    if (s + 1 < 8) CTX_LOAD(a1, b1, s + 1)
    CTX_MF(a0, b0)
    if (s + 2 < 8) CTX_LOAD(a0, b0, s + 2)
    if (s + 1 < 8) CTX_MF(a1, b1)
  }
#undef CTX_LOAD
#undef CTX_MF

  float* sp = Sp + ((long)ns * 128 + bh) * 4096;
  #pragma unroll
  for (int mi = 0; mi < 4; ++mi)
    #pragma unroll
    for (int ni = 0; ni < 4; ++ni)
      #pragma unroll
      for (int r = 0; r < 4; ++r)
        sp[(mi * 16 + lk * 4 + r) * 64 + ni * 16 + lr] = acc[mi][ni][r];
  if (lr == 0) {
    float* zp = Zp + ((long)ns * 128 + bh) * 64;
    #pragma unroll
    for (int mi = 0; mi < 4; ++mi)
      #pragma unroll
      for (int r = 0; r < 4; ++r)
        zp[mi * 16 + lk * 4 + r] = az[mi][r];
  }
}

// ---------- Wc[b,co,h*64+d] = sum_e Wo[co,h*64+e] * (S[d,e]/Z[d])  (bf16 out) ----------
__global__ __launch_bounds__(256) void wc_kernel(
    const float* __restrict__ Sp, const float* __restrict__ Zp,
    const float* __restrict__ Wo, u16* __restrict__ Wc)
{
  int bh = blockIdx.x;            // 128
  int bb = bh >> 3, h = bh & 7;
  __shared__ float Cs[64][65];    // normalized ctx [d][e]
  __shared__ float Ws[64][65];    // Wo chunk [co][e]
  int tid = threadIdx.x, tx = tid & 15, ty = tid >> 4;

  {
    int row = tid >> 2;
    int ec  = (tid & 3) << 4;
    float Zr = 0.f;
    #pragma unroll
    for (int si = 0; si < 16; ++si) Zr += Zp[((long)si * 128 + bh) * 64 + row];
    float invZ = 1.f / Zr;
    #pragma unroll
    for (int u = 0; u < 4; ++u) {
      float4 s = make_float4(0, 0, 0, 0);
      #pragma unroll
      for (int si = 0; si < 16; ++si) {
        float4 tv = *(const float4*)&Sp[(((long)si * 128 + bh) * 64 + row) * 64 + ec + u * 4];
        s.x += tv.x; s.y += tv.y; s.z += tv.z; s.w += tv.w;
      }
      Cs[row][ec + u*4 + 0] = s.x * invZ; Cs[row][ec + u*4 + 1] = s.y * invZ;
      Cs[row][ec + u*4 + 2] = s.z * invZ; Cs[row][ec + u*4 + 3] = s.w * invZ;
    }
  }
  for (int cc = 0; cc < 4; ++cc) {
    __syncthreads();
    {
      int row = tid >> 2;
      int ec  = (tid & 3) << 4;
      #pragma unroll
      for (int u = 0; u < 4; ++u) {
        float4 wv = *(const float4*)&Wo[(long)(cc * 64 + row) * 512 + h * 64 + ec + u * 4];
        Ws[row][ec + u*4 + 0] = wv.x; Ws[row][ec + u*4 + 1] = wv.y;
        Ws[row][ec + u*4 + 2] = wv.z; Ws[row][ec + u*4 + 3] = wv.w;
      }
    }
    __syncthreads();
    float acc[4][4] = {};
    #pragma unroll 8
    for (int e = 0; e < 64; ++e) {
      float a[4], b[4];
      #pragma unroll
      for (int i = 0; i < 4; ++i) a[i] = Ws[(ty << 2) + i][e];
      #pragma unroll
      for (int j = 0; j < 4; ++j) b[j] = Cs[(tx << 2) + j][e];
      #pragma unroll
      for (int i = 0; i < 4; ++i)
        #pragma unroll
        for (int j = 0; j < 4; ++j)
          acc[i][j] += a[i] * b[j];
    }
    #pragma unroll
    for (int i = 0; i < 4; ++i) {
      int co = cc * 64 + (ty << 2) + i;
      ushort4 o;
      o.x = f2bf(acc[i][0]); o.y = f2bf(acc[i][1]);
      o.z = f2bf(acc[i][2]); o.w = f2bf(acc[i][3]);
      *(ushort4*)&Wc[((long)bb * 256 + co) * 512 + h * 64 + (tx << 2)] = o;
    }
  }
}

// ---------- final: out[b] = Wc[b] @ qT[b]^T + bo, swapped operands, float4 stores ----------
__global__ __launch_bounds__(256) void final_gemm(
    const u16* __restrict__ Wc, const u16* __restrict__ qTg,
    const float* __restrict__ bo, float* __restrict__ out)
{
  int b = blockIdx.z;
  const u16* A = Wc + (long)b * (256L * 512);
  const u16* Bm = qTg + (long)b * (4096L * 512);
  int m0 = blockIdx.y * 128, n0 = blockIdx.x * 128;

  __shared__ u16 sm[32768];
  int t = threadIdx.x, w = t >> 6, l = t & 63;
  int lr = l & 15, lk = l >> 4;
  int wr = w >> 1, wcq = w & 1;
  int srow8 = l >> 3;
  int ksl = ((l & 7) ^ srow8) * 8;

  f32x4 acc[4][4];
  #pragma unroll
  for (int i = 0; i < 4; ++i)
    #pragma unroll
    for (int j = 0; j < 4; ++j) acc[i][j] = (f32x4){0.f, 0.f, 0.f, 0.f};

#define STAGE_F(buf, kt) { \
    u16* base_ = sm + (buf) * 16384; \
    int k0_ = (kt) * 64; \
    _Pragma("unroll") \
    for (int i_ = 0; i_ < 4; ++i_) { \
      int seg_ = w * 4 + i_; \
      int row_ = seg_ * 8 + srow8; \
      async16(base_ + seg_ * 512, A + (long)(m0 + row_) * 512 + k0_ + ksl); \
      async16(base_ + 8192 + seg_ * 512, Bm + (long)(n0 + row_) * 512 + k0_ + ksl); \
    } }

#define COMPUTE_F(buf) { \
    const u16* base_ = sm + (buf) * 16384; \
    _Pragma("unroll") \
    for (int s_ = 0; s_ < 2; ++s_) { \
      bf16x8 af_[4], bf_[4]; \
      _Pragma("unroll") \
      for (int mi_ = 0; mi_ < 4; ++mi_) { \
        int row_ = wr * 64 + mi_ * 16 + lr; \
        int slot_ = (s_ * 4 + lk) ^ (row_ & 7); \
        af_[mi_] = *(const bf16x8*)&base_[row_ * 64 + slot_ * 8]; \
      } \
      _Pragma("unroll") \
      for (int ni_ = 0; ni_ < 4; ++ni_) { \
        int row_ = wcq * 64 + ni_ * 16 + lr; \
        int slot_ = (s_ * 4 + lk) ^ (row_ & 7); \
        bf_[ni_] = *(const bf16x8*)&base_[8192 + row_ * 64 + slot_ * 8]; \
      } \
      _Pragma("unroll") \
      for (int mi_ = 0; mi_ < 4; ++mi_) \
        _Pragma("unroll") \
        for (int ni_ = 0; ni_ < 4; ++ni_) \
          acc[mi_][ni_] = __builtin_amdgcn_mfma_f32_16x16x32_bf16(bf_[ni_], af_[mi_], acc[mi_][ni_], 0, 0, 0); \
    } }

  STAGE_F(0, 0)
  STAGE_F(1, 1)
  VW8 BAR
  #pragma unroll
  for (int kt = 0; kt < 8; ++kt) {
    if ((kt & 1) == 0) { COMPUTE_F(0) } else { COMPUTE_F(1) }
    BAR
    if (kt < 6) {
      if ((kt & 1) == 0) { STAGE_F(0, kt + 2) } else { STAGE_F(1, kt + 2) }
      VW8 BAR
    } else if (kt == 6) {
      VW0 BAR
    }
  }

  // swapped epilogue: acc[mi][ni] -> n = n0+wcq*64+ni*16+lk*4+r, m = m0+wr*64+mi*16+lr
  float* op = out + (long)b * (256L * 4096);
  #pragma unroll
  for (int mi = 0; mi < 4; ++mi) {
    int m = m0 + wr * 64 + mi * 16 + lr;
    float bi = bo[m];
    float* rowp = op + (long)m * 4096;
    #pragma unroll
    for (int ni = 0; ni < 4; ++ni) {
      int nb2 = n0 + wcq * 64 + ni * 16 + lk * 4;
      f32x4 v = acc[mi][ni];
      *(float4*)&rowp[nb2] = make_float4(v[0] + bi, v[1] + bi, v[2] + bi, v[3] + bi);
    }
  }
#undef STAGE_F
#undef COMPUTE_F
}

// ---------- launch ----------
extern "C" void kernel_launch(void* const* d_in, const int* in_sizes, int n_in,
                              void* d_out, int out_size, void* d_ws, size_t ws_size,
                              hipStream_t stream) {
  (void)in_sizes; (void)n_in; (void)out_size; (void)ws_size;
  const float* x  = (const float*)d_in[0];
  const float* Wq = (const float*)d_in[1];
  const float* bq = (const float*)d_in[2];
  const float* Wk = (const float*)d_in[3];
  const float* bk = (const float*)d_in[4];
  const float* Wv = (const float*)d_in[5];
  const float* bv = (const float*)d_in[6];
  const float* Wo = (const float*)d_in[7];
  const float* bo = (const float*)d_in[8];
  float* out = (float*)d_out;

  char* ws = (char*)d_ws;
  u16*   xT    = (u16*)(ws);                  // 32MB [16][4096][256]; dead after proj
  float* Sp    = (float*)(ws);                // 32MB [16][128][64][64] aliases xT
  u16*   qT    = (u16*)(ws + 33554432L);      // 64MB [16][4096][512]
  u16*   kx    = (u16*)(ws + 100663296L);     // 64MB [16][512][4096] exp(k)
  u16*   Wcb   = (u16*)(ws + 167772160L);     // 4MB  [16][256][512] bf16
  u16*   Wqkvb = (u16*)(ws + 171966464L);     // 768KB [1536][256] bf16
  float* bqkv  = (float*)(ws + 172752896L);   // 6KB  [1536]
  float* Zp    = (float*)(ws + 172759040L);   // 512KB [16][128][64]
  u16*   vb    = (u16*)d_out;                 // 64MB scratch; dead before final writes

  dim3 blk(256);
  hipLaunchKernelGGL(transpose_x, dim3(64, 4, NB), blk, 0, stream, x, xT);
  hipLaunchKernelGGL(convert_wqkv, dim3(97), blk, 0, stream, Wq, Wk, Wv, bq, bk, bv, Wqkvb, bqkv);
  hipLaunchKernelGGL(HIP_KERNEL_NAME(proj_kern<0>), dim3(32, 4, NB), blk, 0, stream,
                     Wqkvb, bqkv, xT, qT, kx, vb);
  hipLaunchKernelGGL(HIP_KERNEL_NAME(proj_kern<1>), dim3(32, 8, NB), blk, 0, stream,
                     Wqkvb, bqkv, xT, qT, kx, vb);
  hipLaunchKernelGGL(ctx_mfma, dim3(16, 128), dim3(64), 0, stream, kx, vb, Sp, Zp);
  hipLaunchKernelGGL(wc_kernel, dim3(128), blk, 0, stream, Sp, Zp, Wo, Wcb);
  hipLaunchKernelGGL(final_gemm, dim3(32, 2, NB), blk, 0, stream, Wcb, qT, bo, out);
}